// Round 5
// baseline (158.125 us; speedup 1.0000x reference)
//
#include <hip/hip_runtime.h>
#include <hip/hip_bf16.h>

// GNNRefiner: out = xyz + max_k( relu([x_i, x_j-x_i]·W1 + b1)·W2 + b2 )
// Factorization: e·W1 = x_i·(A-B) + x_j·B  with A=W1[0:387], B=W1[387:774].
// Pipeline: prep(fused) -> knn (two-pass exact fp32, radix-select T, reg prefetch)
//           -> bf16 MFMA GEMM (+b1 fused) -> final (k-parallel gather/max, DPP reduce).

#define N 8192
#define NTILES 32   // N/256
#define TD 384      // TOKEN_DIM
#define KNN 16
#define DX 387      // TD + 3
#define KP 416      // DX padded to multiple of 32
#define NF 768      // 2*TD output cols of fused GEMM
#define INFF __builtin_inff()

typedef __attribute__((ext_vector_type(8))) short short8;
typedef __attribute__((ext_vector_type(4))) float f32x4;
typedef __attribute__((ext_vector_type(2))) float f32x2;

// ---------------- packed fp32 helpers (bit-identical to scalar ops, 2 cands/instr) ----------------

__device__ __forceinline__ f32x2 pk_mul(f32x2 a, f32x2 b) {
    f32x2 r; asm("v_pk_mul_f32 %0, %1, %2" : "=v"(r) : "v"(a), "v"(b)); return r;
}
__device__ __forceinline__ f32x2 pk_add(f32x2 a, f32x2 b) {
    f32x2 r; asm("v_pk_add_f32 %0, %1, %2" : "=v"(r) : "v"(a), "v"(b)); return r;
}
__device__ __forceinline__ f32x2 pk_sub(f32x2 a, f32x2 b) {  // a - b, same rounding as fsub
    f32x2 r; asm("v_pk_add_f32 %0, %1, %2 neg_lo:[0,1] neg_hi:[0,1]" : "=v"(r) : "v"(a), "v"(b)); return r;
}
__device__ __forceinline__ f32x2 pk_fma(f32x2 a, f32x2 b, f32x2 c) {
    f32x2 r; asm("v_pk_fma_f32 %0, %1, %2, %3" : "=v"(r) : "v"(a), "v"(b), "v"(c)); return r;
}

// d2 = (qw + sq_j) - 2*dot, dot = fma(qz,z, fma(qy,y, mul(qx,x)))  [bit-identical to ref]
__device__ __forceinline__ void dist4(f32x2 qx, f32x2 qy, f32x2 qz, f32x2 qw,
                                      f32x2 x01, f32x2 x23, f32x2 y01, f32x2 y23,
                                      f32x2 z01, f32x2 z23, f32x2 s01, f32x2 s23,
                                      f32x2& d01, f32x2& d23) {
    f32x2 dot01 = pk_fma(qz, z01, pk_fma(qy, y01, pk_mul(qx, x01)));
    f32x2 dot23 = pk_fma(qz, z23, pk_fma(qy, y23, pk_mul(qx, x23)));
    d01 = pk_sub(pk_add(qw, s01), pk_add(dot01, dot01));  // dot+dot == 2*dot exactly
    d23 = pk_sub(pk_add(qw, s23), pk_add(dot23, dot23));
}

// ---------------- fused prep: Xb rows + point tiles + Wpt ----------------

__global__ void prep_all(const float* __restrict__ feat, const float* __restrict__ xyz,
                         const float* __restrict__ W1,
                         float* __restrict__ tiles, __hip_bfloat16* __restrict__ Xb,
                         __hip_bfloat16* __restrict__ Wpt) {
    int b = blockIdx.x;
    int t = threadIdx.x;
    if (b < N) {
        if (t < 96) {  // vectorized feat copy: 96 x float4 -> 4 x bf16
            float4 f = reinterpret_cast<const float4*>(feat + (size_t)b*TD)[t];
            __hip_bfloat16 h[4] = {__float2bfloat16(f.x), __float2bfloat16(f.y),
                                   __float2bfloat16(f.z), __float2bfloat16(f.w)};
            *reinterpret_cast<ulonglong1*>(Xb + b*KP + t*4) = *reinterpret_cast<ulonglong1*>(h);
        } else if (t == 96) {  // xyz tail + zero pad
            for (int d = TD; d < KP; ++d) {
                float v = (d < DX) ? xyz[b*3 + (d - TD)] : 0.f;
                Xb[b*KP + d] = __float2bfloat16(v);
            }
        } else if (t == 97) {  // point tile entry
            float x = xyz[b*3+0], y = xyz[b*3+1], z = xyz[b*3+2];
            float sq = __fadd_rn(__fadd_rn(__fmul_rn(x,x), __fmul_rn(y,y)), __fmul_rn(z,z));
            float* tp = tiles + (b >> 8) * 1024 + (b & 255);
            tp[0] = x; tp[256] = y; tp[512] = z; tp[768] = sq;
        }
    } else {
        int f = b - N;  // 0..767
        for (int k = t; k < KP; k += 256) {
            float v = 0.f;
            if (k < DX) {
                if (f < TD) v = W1[k*TD + f] - W1[(DX+k)*TD + f];
                else        v = W1[(DX+k)*TD + (f - TD)];
            }
            Wpt[f*KP + k] = __float2bfloat16(v);
        }
    }
}

// ---------------- knn helpers ----------------

__device__ __forceinline__ float dpp_shr1_f(float v) {
    return __uint_as_float((unsigned)__builtin_amdgcn_update_dpp(
        (int)__float_as_uint(v), (int)__float_as_uint(v), 0x111, 0xF, 0xF, false));
}
__device__ __forceinline__ int dpp_shr1_i(int v) {
    return __builtin_amdgcn_update_dpp(v, v, 0x111, 0xF, 0xF, false);
}
__device__ __forceinline__ float rdlane_f(float v, int src) {
    return __uint_as_float(__builtin_amdgcn_readlane(__float_as_uint(v), src));
}

// Sorted-by-lane top-16 insert: list element s in lane s (s=0..15), ascending (d2, idx).
__device__ __forceinline__ void insert16(float dv, int jbase, float Tq,
                                         float& ld, int& li, float& Tl, int lane) {
    unsigned long long m = __ballot((dv <= Tq) && (dv < Tl));
    while (m) {
        int src = (int)__ffsll(m) - 1;
        float cd = rdlane_f(dv, src);
        int   cj = jbase + src*4;
        bool lt = (ld < cd) || (ld == cd && li < cj);
        int pos = (int)__popcll(__ballot(lt) & 0xFFFFull);
        float ud = dpp_shr1_f(ld);
        int   ui = dpp_shr1_i(li);
        ld = (lane == pos) ? cd : ((lane > pos) ? ud : ld);
        li = (lane == pos) ? cj : ((lane > pos) ? ui : li);
        Tl = rdlane_f(ld, 15);
        m &= ~(1ull << src);
        m &= __ballot(dv < Tl);
    }
}

// ---------------- knn: one wave per 4 queries, two-pass, reg-prefetch ----------------

__global__ void __launch_bounds__(256) knn_kernel(const float* __restrict__ tiles,
                                                  int* __restrict__ knn) {
    const int lane = threadIdx.x & 63;
    const int wv   = threadIdx.x >> 6;
    const int i0   = (blockIdx.x * 4 + wv) * 4;   // 4 consecutive queries
    const int st   = i0 >> 8;
    const int sl   = (i0 & 255) >> 2;             // self lane; query q -> slot q

    const float* qp = tiles + st * 1024 + (i0 & 255);
    float4 QX = *(const float4*)(qp);
    float4 QY = *(const float4*)(qp + 256);
    float4 QZ = *(const float4*)(qp + 512);
    float4 QW = *(const float4*)(qp + 768);
    f32x2 qx2[4], qy2[4], qz2[4], qw2[4];
    {
        float qxa[4] = {QX.x,QX.y,QX.z,QX.w}, qya[4] = {QY.x,QY.y,QY.z,QY.w};
        float qza[4] = {QZ.x,QZ.y,QZ.z,QZ.w}, qwa[4] = {QW.x,QW.y,QW.z,QW.w};
        #pragma unroll
        for (int q = 0; q < 4; ++q) {
            qx2[q] = (f32x2){qxa[q], qxa[q]};
            qy2[q] = (f32x2){qya[q], qya[q]};
            qz2[q] = (f32x2){qza[q], qza[q]};
            qw2[q] = (f32x2){qwa[q], qwa[q]};
        }
    }

    const float* lbase = tiles + lane*4;
    const bool is_self_lane = (lane == sl);

    // ---- pass 1: per-lane minima (prefetch next tile; wraps to 0 at end) ----
    float mn[4] = {INFF, INFF, INFF, INFF};
    float4 X = *(const float4*)(lbase);
    float4 Y = *(const float4*)(lbase + 256);
    float4 Z = *(const float4*)(lbase + 512);
    float4 S = *(const float4*)(lbase + 768);
    for (int t = 0; t < NTILES; ++t) {
        const float* np = lbase + ((t+1) & 31) * 1024;
        float4 Xn = *(const float4*)(np);
        float4 Yn = *(const float4*)(np + 256);
        float4 Zn = *(const float4*)(np + 512);
        float4 Sn = *(const float4*)(np + 768);

        f32x2 x01 = {X.x,X.y}, x23 = {X.z,X.w};
        f32x2 y01 = {Y.x,Y.y}, y23 = {Y.z,Y.w};
        f32x2 z01 = {Z.x,Z.y}, z23 = {Z.z,Z.w};
        f32x2 s01 = {S.x,S.y}, s23 = {S.z,S.w};
        const bool selft = (t == st) && is_self_lane;
        #pragma unroll
        for (int q = 0; q < 4; ++q) {
            f32x2 d01, d23;
            dist4(qx2[q], qy2[q], qz2[q], qw2[q],
                  x01, x23, y01, y23, z01, z23, s01, s23, d01, d23);
            if (selft) {
                if      (q == 0) d01[0] = INFF;
                else if (q == 1) d01[1] = INFF;
                else if (q == 2) d23[0] = INFF;
                else             d23[1] = INFF;
            }
            mn[q] = fminf(mn[q], fminf(fminf(d01[0], d01[1]), fminf(d23[0], d23[1])));
        }
        X = Xn; Y = Yn; Z = Zn; S = Sn;
    }

    // ---- T[q] = exact 16th smallest of 64 lane minima, radix-select (no LDS ops) ----
    unsigned ub[4];
    unsigned long long alive[4];
    int need[4];
    #pragma unroll
    for (int q = 0; q < 4; ++q) {
        unsigned x = __float_as_uint(mn[q]);
        ub[q] = ((int)x < 0) ? ~x : (x | 0x80000000u);
        alive[q] = ~0ull;
        need[q] = KNN;
    }
    for (int b = 31; b >= 0; --b) {
        #pragma unroll
        for (int q = 0; q < 4; ++q) {
            unsigned long long ones  = __ballot(((ub[q] >> b) & 1u) != 0u);
            unsigned long long zeros = alive[q] & ~ones;
            int cz = (int)__popcll(zeros);
            bool tz = (cz >= need[q]);
            alive[q] = tz ? zeros : (alive[q] & ones);
            need[q]  = tz ? need[q] : (need[q] - cz);
        }
    }
    float T[4];
    #pragma unroll
    for (int q = 0; q < 4; ++q)
        T[q] = rdlane_f(mn[q], (int)__ffsll(alive[q]) - 1);

    // ---- pass 2: exact top-16 over prefiltered candidates (X..S hold tile 0 again) ----
    float ld[4] = {INFF, INFF, INFF, INFF};
    int   li[4] = {-1, -1, -1, -1};
    float Tl[4] = {INFF, INFF, INFF, INFF};

    for (int t = 0; t < NTILES; ++t) {
        const float* np = lbase + ((t+1) & 31) * 1024;
        float4 Xn = *(const float4*)(np);
        float4 Yn = *(const float4*)(np + 256);
        float4 Zn = *(const float4*)(np + 512);
        float4 Sn = *(const float4*)(np + 768);

        f32x2 x01 = {X.x,X.y}, x23 = {X.z,X.w};
        f32x2 y01 = {Y.x,Y.y}, y23 = {Y.z,Y.w};
        f32x2 z01 = {Z.x,Z.y}, z23 = {Z.z,Z.w};
        f32x2 s01 = {S.x,S.y}, s23 = {S.z,S.w};
        const bool selft = (t == st) && is_self_lane;
        #pragma unroll
        for (int q = 0; q < 4; ++q) {
            f32x2 d01, d23;
            dist4(qx2[q], qy2[q], qz2[q], qw2[q],
                  x01, x23, y01, y23, z01, z23, s01, s23, d01, d23);
            if (selft) {
                if      (q == 0) d01[0] = INFF;
                else if (q == 1) d01[1] = INFF;
                else if (q == 2) d23[0] = INFF;
                else             d23[1] = INFF;
            }
            float tmin = fminf(fminf(d01[0], d01[1]), fminf(d23[0], d23[1]));
            if (__ballot(tmin <= T[q])) {
                insert16(d01[0], t*256 + 0, T[q], ld[q], li[q], Tl[q], lane);
                insert16(d01[1], t*256 + 1, T[q], ld[q], li[q], Tl[q], lane);
                insert16(d23[0], t*256 + 2, T[q], ld[q], li[q], Tl[q], lane);
                insert16(d23[1], t*256 + 3, T[q], ld[q], li[q], Tl[q], lane);
            }
        }
        X = Xn; Y = Yn; Z = Zn; S = Sn;
    }
    if (lane < KNN) {
        #pragma unroll
        for (int q = 0; q < 4; ++q)
            knn[(i0 + q)*KNN + lane] = li[q];
    }
}

// ---------------- GEMM: Cb[N][768] = Xb @ Wpt^T (+ b1 on U-half), bf16 out ----------------
// 1 wave per block, 64 rows x 64 cols; C/D: col = lane&15, row = (lane>>4)*4 + q

__global__ void __launch_bounds__(64) gemm_kernel(const __hip_bfloat16* __restrict__ Xb,
                                                  const __hip_bfloat16* __restrict__ Wpt,
                                                  const float* __restrict__ b1,
                                                  __hip_bfloat16* __restrict__ Cb) {
    const int lane = threadIdx.x;
    const int i0   = blockIdx.x * 64;
    const int f0   = blockIdx.y * 64;
    const int lm   = lane & 15;
    const int lk   = (lane >> 4) * 8;

    f32x4 acc[4][4];
    #pragma unroll
    for (int r = 0; r < 4; ++r)
        #pragma unroll
        for (int c = 0; c < 4; ++c)
            acc[r][c] = (f32x4){0.f, 0.f, 0.f, 0.f};

    const __hip_bfloat16* xbase = Xb  + (size_t)(i0 + lm) * KP + lk;
    const __hip_bfloat16* wbase = Wpt + (size_t)(f0 + lm) * KP + lk;

    #pragma unroll
    for (int kk = 0; kk < 13; ++kk) {
        short8 a[4], b[4];
        #pragma unroll
        for (int r = 0; r < 4; ++r)
            a[r] = *reinterpret_cast<const short8*>(xbase + (size_t)r*16*KP + kk*32);
        #pragma unroll
        for (int c = 0; c < 4; ++c)
            b[c] = *reinterpret_cast<const short8*>(wbase + (size_t)c*16*KP + kk*32);
        #pragma unroll
        for (int r = 0; r < 4; ++r)
            #pragma unroll
            for (int c = 0; c < 4; ++c)
                acc[r][c] = __builtin_amdgcn_mfma_f32_16x16x32_bf16(a[r], b[c], acc[r][c], 0, 0, 0);
    }

    float bias[4] = {0.f, 0.f, 0.f, 0.f};
    if (f0 < TD) {
        #pragma unroll
        for (int c = 0; c < 4; ++c) bias[c] = b1[f0 + c*16 + lm];
    }
    const int crow = (lane >> 4) * 4;
    #pragma unroll
    for (int r = 0; r < 4; ++r)
        #pragma unroll
        for (int c = 0; c < 4; ++c)
            #pragma unroll
            for (int q = 0; q < 4; ++q)
                Cb[(size_t)(i0 + r*16 + crow + q) * NF + f0 + c*16 + lm] =
                    __float2bfloat16(acc[r][c][q] + bias[c]);
}

// ---------------- final: k-parallel, lane = (k, dim-quarter), DPP reduce ----------------

__device__ __forceinline__ float bflo(unsigned w) { return __uint_as_float(w << 16); }
__device__ __forceinline__ float bfhi(unsigned w) { return __uint_as_float(w & 0xFFFF0000u); }

template<int CTRL>
__device__ __forceinline__ float dppf(float v) {
    return __uint_as_float((unsigned)__builtin_amdgcn_update_dpp(
        0, (int)__float_as_uint(v), CTRL, 0xF, 0xF, true));
}

__global__ void __launch_bounds__(256) final_kernel(const __hip_bfloat16* __restrict__ Cb,
                                                    const int* __restrict__ knn,
                                                    const float* __restrict__ xyz,
                                                    const float* __restrict__ W2,
                                                    const float* __restrict__ b2,
                                                    float* __restrict__ out) {
    const int lane = threadIdx.x & 63;
    const int wv   = threadIdx.x >> 6;
    const int i    = blockIdx.x * 4 + wv;
    const int k    = lane >> 2;       // neighbor slot 0..15
    const int qt   = lane & 3;        // dim quarter 0..3 (96 dims each)

    const int j = knn[i*KNN + k];
    const uint4*  V = reinterpret_cast<const uint4*>(Cb + (size_t)j * NF + TD + qt*96);
    const uint4*  U = reinterpret_cast<const uint4*>(Cb + (size_t)i * NF + qt*96);
    const float4* W = reinterpret_cast<const float4*>(W2 + (size_t)qt*96*3);

    float s0 = 0.f, s1 = 0.f, s2 = 0.f;
    #pragma unroll
    for (int cc = 0; cc < 12; ++cc) {   // 8 dims per chunk
        uint4 vv = V[cc];
        uint4 uu = U[cc];
        float w[24];
        #pragma unroll
        for (int p = 0; p < 6; ++p) {
            float4 wp = W[cc*6 + p];
            w[p*4+0] = wp.x; w[p*4+1] = wp.y; w[p*4+2] = wp.z; w[p*4+3] = wp.w;
        }
        unsigned va[4] = {vv.x, vv.y, vv.z, vv.w};
        unsigned ua[4] = {uu.x, uu.y, uu.z, uu.w};
        #pragma unroll
        for (int m = 0; m < 4; ++m) {
            float hlo = fmaxf(bflo(ua[m]) + bflo(va[m]), 0.f);
            float hhi = fmaxf(bfhi(ua[m]) + bfhi(va[m]), 0.f);
            const int d3 = (2*m)*3;
            s0 = fmaf(hlo, w[d3+0], s0);
            s1 = fmaf(hlo, w[d3+1], s1);
            s2 = fmaf(hlo, w[d3+2], s2);
            s0 = fmaf(hhi, w[d3+3], s0);
            s1 = fmaf(hhi, w[d3+4], s1);
            s2 = fmaf(hhi, w[d3+5], s2);
        }
    }
    // sum over the 4 quarter-lanes (quad butterfly, DPP)
    s0 += dppf<0xB1>(s0); s0 += dppf<0x4E>(s0);
    s1 += dppf<0xB1>(s1); s1 += dppf<0x4E>(s1);
    s2 += dppf<0xB1>(s2); s2 += dppf<0x4E>(s2);
    // max over the 16 neighbor-quads: row rotate (4,8) then cross-row shuffles
    s0 = fmaxf(s0, dppf<0x124>(s0)); s0 = fmaxf(s0, dppf<0x128>(s0));
    s1 = fmaxf(s1, dppf<0x124>(s1)); s1 = fmaxf(s1, dppf<0x128>(s1));
    s2 = fmaxf(s2, dppf<0x124>(s2)); s2 = fmaxf(s2, dppf<0x128>(s2));
    s0 = fmaxf(s0, __shfl_xor(s0, 16)); s0 = fmaxf(s0, __shfl_xor(s0, 32));
    s1 = fmaxf(s1, __shfl_xor(s1, 16)); s1 = fmaxf(s1, __shfl_xor(s1, 32));
    s2 = fmaxf(s2, __shfl_xor(s2, 16)); s2 = fmaxf(s2, __shfl_xor(s2, 32));

    if (lane == 0) {
        out[i*3+0] = xyz[i*3+0] + s0 + b2[0];
        out[i*3+1] = xyz[i*3+1] + s1 + b2[1];
        out[i*3+2] = xyz[i*3+2] + s2 + b2[2];
    }
}

// ---------------- launch ----------------

extern "C" void kernel_launch(void* const* d_in, const int* in_sizes, int n_in,
                              void* d_out, int out_size, void* d_ws, size_t ws_size,
                              hipStream_t stream) {
    const float* xyz  = (const float*)d_in[0];
    const float* feat = (const float*)d_in[1];
    const float* W1   = (const float*)d_in[2];
    const float* b1   = (const float*)d_in[3];
    const float* W2   = (const float*)d_in[4];
    const float* b2   = (const float*)d_in[5];
    float* out = (float*)d_out;

    char* ws = (char*)d_ws;
    int*            knn   = (int*)(ws + 0);                  //   524288 B
    float*          tiles = (float*)(ws + 524288);           //   131072 B
    __hip_bfloat16* Xb    = (__hip_bfloat16*)(ws + 655360);  //  6815744 B
    __hip_bfloat16* Wpt   = (__hip_bfloat16*)(ws + 7471104); //   638976 B
    __hip_bfloat16* Cb    = (__hip_bfloat16*)(ws + 8110080); // 12582912 B -> end 20692992

    prep_all   <<<dim3(N + NF),      dim3(256), 0, stream>>>(feat, xyz, W1, tiles, Xb, Wpt);
    knn_kernel <<<dim3(N/16),        dim3(256), 0, stream>>>(tiles, knn);
    gemm_kernel<<<dim3(N/64, NF/64), dim3(64),  0, stream>>>(Xb, Wpt, b1, Cb);
    final_kernel<<<dim3(N/4),        dim3(256), 0, stream>>>(Cb, knn, xyz, W2, b2, out);
}